// Round 16
// baseline (864.951 us; speedup 1.0000x reference)
//
#include <hip/hip_runtime.h>

#define NN 50000
#define EE 800000
#define TT 12
#define HH 128
#define LLAYERS 3
#define OO 12

#define GRU_TILES 782      // ceil(NN/64)
#define GRU_GRID  768      // 3 * 256 CUs exactly
#define FILLB     1563     // (EE+511)/512
#define SORTB     98       // (NN+511)/512

typedef __attribute__((ext_vector_type(8))) short short8;    // 8 bf16 = 4 VGPRs
typedef __attribute__((ext_vector_type(4))) float float4v;   // MFMA acc
typedef unsigned short ushort_t;

#define MFMA_BF16 __builtin_amdgcn_mfma_f32_16x16x32_bf16

#define L2E  1.4426950408889634f
#define L2E2 2.8853900817779268f

#if __has_builtin(__builtin_amdgcn_exp2f)
#define EXP2(x) __builtin_amdgcn_exp2f(x)
#else
#define EXP2(x) __expf((x) * 0.6931471805599453f)
#endif

__device__ __forceinline__ ushort_t f2b(float f) {   // fp32 -> bf16 RNE
    union { float f; unsigned u; } v; v.f = f;
    unsigned u = v.u;
    return (ushort_t)((u + 0x7FFFu + ((u >> 16) & 1u)) >> 16);
}
__device__ __forceinline__ float b2f(ushort_t b) {
    union { unsigned u; float f; } v; v.u = ((unsigned)b) << 16; return v.f;
}
__device__ __forceinline__ short8 ld8(const ushort_t* p) { return *(const short8*)p; }

__device__ __forceinline__ float rcpf_(float x) { return __builtin_amdgcn_rcpf(x); }
// Inputs pre-scaled: y = log2e * x_true  -> sigmoid(x_true)
__device__ __forceinline__ float sig2(float y) { return rcpf_(1.f + EXP2(-y)); }
// y = 2*log2e * x_true -> tanh(x_true)
__device__ __forceinline__ float tanh2(float y) {
    return fmaf(2.f, rcpf_(1.f + EXP2(-y)), -1.f);
}

// Old-style [R][128] tile helpers (used by fc_head only; R<=32).
__device__ __forceinline__ short8 lds_frag(const ushort_t* tile, int row, int kb) {
    int off = (row << 8) + kb;
    off ^= (row & 7) << 4;
    return *(const short8*)((const char*)tile + off);
}
__device__ __forceinline__ void lds_wr16(ushort_t* tile, int row, int cb, ushort_t v) {
    int off = (row << 8) + cb;
    off ^= (row & 7) << 4;
    *(ushort_t*)((char*)tile + off) = v;
}

#define MSTRIDE 132   // fp32 master stride: bank=(4rl+jj)%32 -> free 2-way only

// ---------------------------------------------------------------------------
// Persistent 2-layer GRU + csr_fill + degree-sort-scatter piggyback.
// Blocks [0,768): GRU, tiles {b, b+768 if < 782} (64 nodes each). Weight
// fragments (144 regs, exp2-prescaled) loaded ONCE, reused across tiles.
// Blocks [768,768+FILLB): csr_fill edge scatter (packed (src,ea) int2).
// Blocks [768+FILLB,...): degree-sort scatter -> perm (for gat scheduling).
// One barrier per t-step. fp32 masters in LDS. Both rt loops unrolled 2x.
// ---------------------------------------------------------------------------
__global__ __launch_bounds__(512, 2)
void gru_all(const float* __restrict__ x,
             const ushort_t* __restrict__ Whh0b, const float* __restrict__ Wih0,
             const float* __restrict__ bih0, const float* __restrict__ bhh0,
             const ushort_t* __restrict__ Wih1b, const ushort_t* __restrict__ Whh1b,
             const float* __restrict__ bih1, const float* __restrict__ bhh1,
             float* __restrict__ h1f, ushort_t* __restrict__ h1b,
             const int* __restrict__ src, const int* __restrict__ dst,
             const float* __restrict__ ea, int* __restrict__ cursor,
             int2* __restrict__ edgeS,
             const int* __restrict__ deg, int* __restrict__ dcur,
             int* __restrict__ perm) {
    __shared__ ushort_t h0sA[9216], h0sB[9216], h1sA[9216], h1sB[9216]; // 18432 B each
    __shared__ float h0m[64 * MSTRIDE], h1m[64 * MSTRIDE];              // 33792 B each
    __shared__ float xsh[768];                                          // [12][64]

    // ---- degree-sort scatter blocks (run in GRU stagger) ----
    if (blockIdx.x >= GRU_GRID + FILLB) {
        int n = (blockIdx.x - GRU_GRID - FILLB) * 512 + threadIdx.x;
        if (n < NN) {
            int b = min(deg[n], 511);
            int pos = atomicAdd(&dcur[b], 1);
            perm[pos] = n;
        }
        return;
    }
    // ---- csr_fill blocks (uniform per-block branch; no barriers used) ----
    if (blockIdx.x >= GRU_GRID) {
        int e = (blockIdx.x - GRU_GRID) * 512 + threadIdx.x;
        if (e < EE) {
            int pos = atomicAdd(&cursor[dst[e]], 1);
            edgeS[pos] = make_int2(src[e], __float_as_int(ea[e]));
        }
        return;
    }

    const int tid = threadIdx.x;
    const int wv = tid >> 6, lane = tid & 63;
    const int cl = lane & 15, kg = lane >> 4;
    const int jj = wv * 16 + cl;          // owned hidden column

    // --- persistent weight fragments (loaded once; R/Z rows pre-scaled by
    //     log2e, N rows by 2*log2e in conv_cnt) ---
    short8 w0[3][4], wxx[3][4], whh[3][4];
#pragma unroll
    for (int g = 0; g < 3; ++g)
#pragma unroll
        for (int ks = 0; ks < 4; ++ks) {
            const size_t ro = (size_t)(g * 128 + jj) * HH + ks * 32 + kg * 8;
            w0[g][ks]  = ld8(Whh0b + ro);
            wxx[g][ks] = ld8(Wih1b + ro);
            whh[g][ks] = ld8(Whh1b + ro);
        }
    const float wiR = Wih0[jj] * L2E, wiZ = Wih0[jj + 128] * L2E, wiN = Wih0[jj + 256] * L2E2;
    const float b0R = (bih0[jj] + bhh0[jj]) * L2E;
    const float b0Z = (bih0[jj + 128] + bhh0[jj + 128]) * L2E;
    const float b0N = bih0[jj + 256] * L2E2;
    const float c0N = bhh0[jj + 256] * L2E2;
    const float b1R = (bih1[jj] + bhh1[jj]) * L2E;
    const float b1Z = (bih1[jj + 128] + bhh1[jj + 128]) * L2E;
    const float b1N = bih1[jj + 256] * L2E2;
    const float c1N = bhh1[jj + 256] * L2E2;

    // LDS address precompute
    const int rdl = kg * 288 + cl * 16;                      // + ks*4608 + rt*1152
    const int ksw = jj >> 5;
    const int kcw = (jj >> 3) & 3;
    const int wbase = (ksw * 16 + kcw) * 288 + kg * 64 + (jj & 7) * 2; // + rt*1152 + i*16

#pragma unroll 1
    for (int tile = blockIdx.x; tile < GRU_TILES; tile += GRU_GRID) {
        const int r0 = tile * 64;

        for (int q = tid; q < 768; q += 512) {
            int tt = q >> 6, row = q & 63;                   // xsh[t][row]
            int node = r0 + row;
            xsh[q] = (node < NN) ? x[(size_t)node * TT + tt] : 0.f;
        }
        // zero only the A buffers (B buffers fully written before first read;
        // after 12 swaps (even) pointers return to A for the next tile)
        for (int q = tid; q < 4608; q += 512) {
            ((unsigned*)h0sA)[q] = 0u; ((unsigned*)h1sA)[q] = 0u;
        }
        for (int q = tid; q < 64 * MSTRIDE; q += 512) { h0m[q] = 0.f; h1m[q] = 0.f; }
        __syncthreads();

        ushort_t* h0c = h0sA; ushort_t* h0n = h0sB;
        ushort_t* h1c = h1sA; ushort_t* h1n = h1sB;

#pragma unroll 1
        for (int t = 0; t < TT; ++t) {
            const float* xrow = xsh + t * 64;
            // ---------------- layer 0: read h0c, write h0n ----------------
#pragma unroll 2
            for (int rt = 0; rt < 4; ++rt) {
                short8 a[4];
#pragma unroll
                for (int ks = 0; ks < 4; ++ks)
                    a[ks] = *(const short8*)((const char*)h0c + ks * 4608 + rt * 1152 + rdl);
                float4v aR = {0,0,0,0}, aZ = {0,0,0,0}, aN = {0,0,0,0};
#pragma unroll
                for (int ks = 0; ks < 4; ++ks) {
                    aR = MFMA_BF16(a[ks], w0[0][ks], aR, 0, 0, 0);
                    aZ = MFMA_BF16(a[ks], w0[1][ks], aZ, 0, 0, 0);
                    aN = MFMA_BF16(a[ks], w0[2][ks], aN, 0, 0, 0);
                }
#pragma unroll
                for (int i = 0; i < 4; ++i) {
                    const int rl = rt * 16 + kg * 4 + i;
                    float xv = xrow[rl];
                    float hold = h0m[rl * MSTRIDE + jj];
                    float r = sig2(fmaf(xv, wiR, b0R) + aR[i]);
                    float z = sig2(fmaf(xv, wiZ, b0Z) + aZ[i]);
                    float nn2 = tanh2(fmaf(xv, wiN, b0N) + r * (aN[i] + c0N));
                    float hn = fmaf(z, hold - nn2, nn2);
                    h0m[rl * MSTRIDE + jj] = hn;
                    *(ushort_t*)((char*)h0n + wbase + rt * 1152 + i * 16) = f2b(hn);
                }
            }
            __syncthreads();   // the ONLY barrier per t-step
            // ---------------- layer 1: read h0n,h1c, write h1n ----------------
#pragma unroll 2
            for (int rt = 0; rt < 4; ++rt) {
                short8 an[4], a1[4];
#pragma unroll
                for (int ks = 0; ks < 4; ++ks) {
                    an[ks] = *(const short8*)((const char*)h0n + ks * 4608 + rt * 1152 + rdl);
                    a1[ks] = *(const short8*)((const char*)h1c + ks * 4608 + rt * 1152 + rdl);
                }
                // R/Z: gx+gh accumulate into ONE chain; N needs gh separate.
                float4v gR = {0,0,0,0}, gZ = {0,0,0,0}, xN = {0,0,0,0}, hN = {0,0,0,0};
#pragma unroll
                for (int ks = 0; ks < 4; ++ks) {
                    gR = MFMA_BF16(an[ks], wxx[0][ks], gR, 0, 0, 0);
                    gZ = MFMA_BF16(an[ks], wxx[1][ks], gZ, 0, 0, 0);
                    xN = MFMA_BF16(an[ks], wxx[2][ks], xN, 0, 0, 0);
                    gR = MFMA_BF16(a1[ks], whh[0][ks], gR, 0, 0, 0);
                    gZ = MFMA_BF16(a1[ks], whh[1][ks], gZ, 0, 0, 0);
                    hN = MFMA_BF16(a1[ks], whh[2][ks], hN, 0, 0, 0);
                }
#pragma unroll
                for (int i = 0; i < 4; ++i) {
                    const int rl = rt * 16 + kg * 4 + i;
                    float hold = h1m[rl * MSTRIDE + jj];
                    float r = sig2(gR[i] + b1R);
                    float z = sig2(gZ[i] + b1Z);
                    float nn2 = tanh2(xN[i] + b1N + r * (hN[i] + c1N));
                    float hn = fmaf(z, hold - nn2, nn2);
                    h1m[rl * MSTRIDE + jj] = hn;
                    *(ushort_t*)((char*)h1n + wbase + rt * 1152 + i * 16) = f2b(hn);
                }
            }
            // no barrier: layer0@t+1 only touches h0 buffers whose readers all
            // completed before the barrier above (round-10 proof).
            ushort_t* tmp0 = h0c; h0c = h0n; h0n = tmp0;
            ushort_t* tmp1 = h1c; h1c = h1n; h1n = tmp1;
        }

        // write h1 out (masters owner-lane; no sync needed)
#pragma unroll
        for (int rt = 0; rt < 4; ++rt)
#pragma unroll
            for (int i = 0; i < 4; ++i) {
                const int rl = rt * 16 + kg * 4 + i;
                int node = r0 + rl;
                if (node < NN) {
                    float v = h1m[rl * MSTRIDE + jj];
                    const size_t off = (size_t)node * HH + jj;
                    h1f[off] = v;
                    h1b[off] = f2b(v);
                }
            }
        // barrier before next tile reuses/zeroes the LDS this tile just read
        __syncthreads();
    }
}

// ---------------------------------------------------------------------------
// Dual bf16 GEMM, 32 rows/wave: B-fragments loaded once feed two row-halves.
// ---------------------------------------------------------------------------
__global__ __launch_bounds__(256)
void gemm_dual(const ushort_t* __restrict__ A,
               const ushort_t* __restrict__ B1, const ushort_t* __restrict__ B2,
               const float* __restrict__ bias1, const float* __restrict__ bias2,
               ushort_t* __restrict__ C1, ushort_t* __restrict__ C2) {
    const int wave = threadIdx.x >> 6, lane = threadIdx.x & 63;
    const int r0 = (blockIdx.x * 4 + wave) * 32;
    const int col = lane & 15, kg = lane >> 4;
    const int arow0 = min(r0 + col, NN - 1);
    const int arow1 = min(r0 + 16 + col, NN - 1);
    short8 a0[4], a1[4];
#pragma unroll
    for (int ks = 0; ks < 4; ++ks) {
        a0[ks] = ld8(A + (size_t)arow0 * HH + ks * 32 + kg * 8);
        a1[ks] = ld8(A + (size_t)arow1 * HH + ks * 32 + kg * 8);
    }
#pragma unroll
    for (int j0 = 0; j0 < 8; ++j0) {
        float4v c10 = {0,0,0,0}, c11 = {0,0,0,0}, c20 = {0,0,0,0}, c21 = {0,0,0,0};
        const ushort_t* p1 = B1 + (size_t)(j0 * 16 + col) * HH + kg * 8;
        const ushort_t* p2 = B2 + (size_t)(j0 * 16 + col) * HH + kg * 8;
#pragma unroll
        for (int ks = 0; ks < 4; ++ks) {
            short8 b1v = ld8(p1 + ks * 32);
            short8 b2v = ld8(p2 + ks * 32);
            c10 = MFMA_BF16(a0[ks], b1v, c10, 0, 0, 0);
            c11 = MFMA_BF16(a1[ks], b1v, c11, 0, 0, 0);
            c20 = MFMA_BF16(a0[ks], b2v, c20, 0, 0, 0);
            c21 = MFMA_BF16(a1[ks], b2v, c21, 0, 0, 0);
        }
        const int jj = j0 * 16 + col;
        const float b1 = bias1[jj], b2 = bias2[jj];
#pragma unroll
        for (int i = 0; i < 4; ++i) {
            int node0 = r0 + kg * 4 + i;
            int node1 = node0 + 16;
            if (node0 < NN) {
                C1[(size_t)node0 * HH + jj] = f2b(c10[i] + b1);
                C2[(size_t)node0 * HH + jj] = f2b(c20[i] + b2);
            }
            if (node1 < NN) {
                C1[(size_t)node1 * HH + jj] = f2b(c11[i] + b1);
                C2[(size_t)node1 * HH + jj] = f2b(c21[i] + b2);
            }
        }
    }
}

// ---------------------------------------------------------------------------
// CSR segment allocation (disjoint, not node-ordered). Writes packed
// (rowbeg, deg) int2 and accumulates the degree histogram for the sort.
// ---------------------------------------------------------------------------
__global__ void csr_alloc(const int* __restrict__ deg, int2* __restrict__ rbdeg,
                          int* __restrict__ cursor, int* __restrict__ gcnt,
                          int* __restrict__ dhist) {
    int n = blockIdx.x * 256 + threadIdx.x;
    int ln = threadIdx.x & 63;
    int d = (n < NN) ? deg[n] : 0;
    int s = d;
#pragma unroll
    for (int off = 1; off < 64; off <<= 1) {
        int t = __shfl_up(s, off);
        if (ln >= off) s += t;
    }
    int base = 0;
    if (ln == 63) base = atomicAdd(gcnt, s);
    base = __shfl(base, 63);
    int excl = base + s - d;
    if (n < NN) {
        rbdeg[n] = make_int2(excl, d);
        cursor[n] = excl;
        atomicAdd(&dhist[min(d, 511)], 1);
    }
}

// ---------------------------------------------------------------------------
// 512-bin exclusive scan of the degree histogram -> bin write cursors.
// ---------------------------------------------------------------------------
__global__ __launch_bounds__(512)
void dsort_scan(const int* __restrict__ dhist, int* __restrict__ dcur) {
    __shared__ int wsum[8];
    const int tid = threadIdx.x, ln = tid & 63, wv = tid >> 6;
    int v = dhist[tid];
    int s = v;
#pragma unroll
    for (int d = 1; d < 64; d <<= 1) { int t = __shfl_up(s, d); if (ln >= d) s += t; }
    if (ln == 63) wsum[wv] = s;
    __syncthreads();
    if (tid < 8) {
        int w = wsum[tid];
#pragma unroll
        for (int d = 1; d < 8; d <<= 1) { int u = __shfl_up(w, d); if (tid >= d) w += u; }
        wsum[tid] = w;   // inclusive
    }
    __syncthreads();
    int wof = wv ? wsum[wv - 1] : 0;
    dcur[tid] = wof + s - v;   // exclusive prefix
}

// ---------------------------------------------------------------------------
// Fused GAT (depth-1 prefetch, packed edgeS, DEGREE-SORTED node schedule):
// wave slot -> perm[slot]; a block's 4 waves get near-equal degrees so block
// lifetime ~ mean not max. 4 edges in parallel (16 lanes each, 8 ch/lane).
// No-max softmax. Then bias + LN + ELU + residual (group 0 writes).
// ---------------------------------------------------------------------------
__global__ __launch_bounds__(256)
void gat_fused(const int2* __restrict__ rbdeg,
               const int2* __restrict__ edgeS, const int* __restrict__ perm,
               const ushort_t* __restrict__ xlb, const ushort_t* __restrict__ xrb,
               const float* __restrict__ We, const float* __restrict__ att,
               const float* __restrict__ gbias, const float* __restrict__ gamma,
               const float* __restrict__ beta,
               float* __restrict__ h1f, ushort_t* __restrict__ h1b) {
    const int slot = (blockIdx.x * 256 + threadIdx.x) >> 6;
    const int lane = threadIdx.x & 63;
    if (slot >= NN) return;
    const int node = perm[slot];
    const int g = lane >> 4, gl = lane & 15;
    const int cb = gl * 8;                      // this lane's channel base

    short8 xrv = ld8(xrb + (size_t)node * HH + cb);
    float xr[8], Wv[8], Av[8];
#pragma unroll
    for (int c = 0; c < 8; ++c) xr[c] = b2f((ushort_t)xrv[c]);
    *(float4*)&Wv[0] = *(const float4*)(We + cb);
    *(float4*)&Wv[4] = *(const float4*)(We + cb + 4);
    *(float4*)&Av[0] = *(const float4*)(att + cb);
    *(float4*)&Av[4] = *(const float4*)(att + cb + 4);

    const int2 bd = rbdeg[node];
    const int beg = bd.x;
    const int end = beg + bd.y;
    float acc[8] = {};
    float den = 0.f;

    if (beg < end) {
        // prime the pipeline
        bool valid = (beg + g) < end;
        int es = min(beg + g, end - 1);
        int2 ed = edgeS[es];
        short8 xlv = ld8(xlb + (size_t)ed.x * HH + cb);
        for (int base = beg; base < end; base += 4) {
            // prefetch next group (uniform branch: base/end wave-uniform)
            int nbase = base + 4;
            int2 ed2 = ed; short8 xlv2 = {};
            bool nvalid = false;
            if (nbase < end) {
                nvalid = (nbase + g) < end;
                int nes = min(nbase + g, end - 1);
                ed2 = edgeS[nes];
                xlv2 = ld8(xlb + (size_t)ed2.x * HH + cb);
            }
            // compute current group
            float ev = __int_as_float(ed.y);
            float xl[8];
            float p = 0.f;
#pragma unroll
            for (int c = 0; c < 8; ++c) {
                xl[c] = b2f((ushort_t)xlv[c]);
                float m = xl[c] + xr[c] + ev * Wv[c];
                m = (m > 0.f) ? m : 0.2f * m;
                p = fmaf(m, Av[c], p);
            }
            p += __shfl_xor(p, 1);
            p += __shfl_xor(p, 2);              // head score (4-lane quad)
            float w = valid ? __expf(p) : 0.f;
            den += w;
#pragma unroll
            for (int c = 0; c < 8; ++c) acc[c] = fmaf(w, xl[c], acc[c]);
            // rotate
            valid = nvalid; ed = ed2; xlv = xlv2;
        }
    }
    // cross-group (edge-slot) reduce
#pragma unroll
    for (int c = 0; c < 8; ++c) {
        acc[c] += __shfl_xor(acc[c], 16);
        acc[c] += __shfl_xor(acc[c], 32);
    }
    den += __shfl_xor(den, 16);
    den += __shfl_xor(den, 32);

    float invd = 1.f / fmaxf(den, 1e-16f);
    float gb[8];
    *(float4*)&gb[0] = *(const float4*)(gbias + cb);
    *(float4*)&gb[4] = *(const float4*)(gbias + cb + 4);
    float o[8], s1 = 0.f, s2 = 0.f;
#pragma unroll
    for (int c = 0; c < 8; ++c) {
        o[c] = acc[c] * invd + gb[c];
        s1 += o[c];
        s2 = fmaf(o[c], o[c], s2);
    }
#pragma unroll
    for (int d = 1; d < 16; d <<= 1) {
        s1 += __shfl_xor(s1, d);
        s2 += __shfl_xor(s2, d);
    }
    float mean = s1 * (1.f / 128.f);
    float var = s2 * (1.f / 128.f) - mean * mean;
    float inv = rsqrtf(var + 1e-5f);

    if (g == 0) {
        float gm[8], bt[8], hv[8];
        *(float4*)&gm[0] = *(const float4*)(gamma + cb);
        *(float4*)&gm[4] = *(const float4*)(gamma + cb + 4);
        *(float4*)&bt[0] = *(const float4*)(beta + cb);
        *(float4*)&bt[4] = *(const float4*)(beta + cb + 4);
        *(float4*)&hv[0] = *(const float4*)(h1f + (size_t)node * HH + cb);
        *(float4*)&hv[4] = *(const float4*)(h1f + (size_t)node * HH + cb + 4);
        short8 pk;
#pragma unroll
        for (int c = 0; c < 8; ++c) {
            float y = (o[c] - mean) * inv * gm[c] + bt[c];
            y = (y > 0.f) ? y : expm1f(y);
            hv[c] += y;
            pk[c] = (short)f2b(hv[c]);
        }
        *(float4*)(h1f + (size_t)node * HH + cb)     = *(float4*)&hv[0];
        *(float4*)(h1f + (size_t)node * HH + cb + 4) = *(float4*)&hv[4];
        *(short8*)(h1b + (size_t)node * HH + cb) = pk;
    }
}

// ---------------------------------------------------------------------------
// Fused FC head, 32 rows/wave: out = relu(h1@W1^T+b1) @ W2 + b2 via LDS.
// ---------------------------------------------------------------------------
__global__ __launch_bounds__(256)
void fc_head(const ushort_t* __restrict__ A, const ushort_t* __restrict__ W1b,
             const float* __restrict__ b1, const ushort_t* __restrict__ W2b,
             const float* __restrict__ b2, float* __restrict__ out) {
    __shared__ ushort_t hs[4][4096];   // [32][128] per wave
    const int wave = threadIdx.x >> 6, lane = threadIdx.x & 63;
    const int r0 = (blockIdx.x * 4 + wave) * 32;
    const int col = lane & 15, kg = lane >> 4;
    const int arow0 = min(r0 + col, NN - 1);
    const int arow1 = min(r0 + 16 + col, NN - 1);
    short8 a0[4], a1[4];
#pragma unroll
    for (int ks = 0; ks < 4; ++ks) {
        a0[ks] = ld8(A + (size_t)arow0 * HH + ks * 32 + kg * 8);
        a1[ks] = ld8(A + (size_t)arow1 * HH + ks * 32 + kg * 8);
    }
#pragma unroll
    for (int j0 = 0; j0 < 8; ++j0) {
        float4v acc0 = {0,0,0,0}, acc1 = {0,0,0,0};
        const ushort_t* bp = W1b + (size_t)(j0 * 16 + col) * HH + kg * 8;
#pragma unroll
        for (int ks = 0; ks < 4; ++ks) {
            short8 bv = ld8(bp + ks * 32);
            acc0 = MFMA_BF16(a0[ks], bv, acc0, 0, 0, 0);
            acc1 = MFMA_BF16(a1[ks], bv, acc1, 0, 0, 0);
        }
        const int jj = j0 * 16 + col;
        const float bj = b1[jj];
#pragma unroll
        for (int i = 0; i < 4; ++i) {
            lds_wr16(hs[wave], kg * 4 + i, jj * 2, f2b(fmaxf(acc0[i] + bj, 0.f)));
            lds_wr16(hs[wave], 16 + kg * 4 + i, jj * 2, f2b(fmaxf(acc1[i] + bj, 0.f)));
        }
    }
    // second GEMM: [32,128] @ W2b[16 padded cols][128]
    short8 w2f[4];
#pragma unroll
    for (int ks = 0; ks < 4; ++ks)
        w2f[ks] = ld8(W2b + (size_t)col * HH + ks * 32 + kg * 8);
#pragma unroll
    for (int rh = 0; rh < 2; ++rh) {
        short8 f[4];
#pragma unroll
        for (int ks = 0; ks < 4; ++ks)
            f[ks] = lds_frag(hs[wave], rh * 16 + col, ks * 64 + kg * 16);
        float4v acc2 = {0,0,0,0};
#pragma unroll
        for (int ks = 0; ks < 4; ++ks)
            acc2 = MFMA_BF16(f[ks], w2f[ks], acc2, 0, 0, 0);
        if (col < OO) {
            const float bj = b2[col];
#pragma unroll
            for (int i = 0; i < 4; ++i) {
                int node = r0 + rh * 16 + kg * 4 + i;
                if (node < NN) out[(size_t)node * OO + col] = acc2[i] + bj;
            }
        }
    }
}

// ---------------------------------------------------------------------------
// Merged weight-conversion + csr_count kernel. Blocks [0,1032): conversions
// (GRU rows exp2-prescaled: R/Z by log2e, N rows by 2*log2e). Blocks
// [1032,...): degree histogram (independent work, overlapped).
// ---------------------------------------------------------------------------
__global__ void conv_cnt(const float* __restrict__ Whh0, const float* __restrict__ Wih1,
                         const float* __restrict__ Whh1, const float* __restrict__ gWl,
                         const float* __restrict__ gWr, const float* __restrict__ fcW1,
                         const float* __restrict__ fcW2,
                         ushort_t* __restrict__ Whh0b, ushort_t* __restrict__ Wih1b,
                         ushort_t* __restrict__ Whh1b, ushort_t* __restrict__ WlTb,
                         ushort_t* __restrict__ WrTb, ushort_t* __restrict__ W1Tb,
                         ushort_t* __restrict__ W2Tb,
                         const int* __restrict__ dst, int* __restrict__ deg) {
    if (blockIdx.x >= 1032) {
        int e = (blockIdx.x - 1032) * 256 + threadIdx.x;
        if (e < EE) atomicAdd(&deg[dst[e]], 1);
        return;
    }
    int idx = blockIdx.x * 256 + threadIdx.x;
    if (idx < 147456) {
        const float* s; ushort_t* d; int o = idx;
        if (o < 49152)        { s = Whh0; d = Whh0b; }
        else if (o < 98304)   { s = Wih1; d = Wih1b; o -= 49152; }
        else                  { s = Whh1; d = Whh1b; o -= 98304; }
        float scale = (o >= 256 * 128) ? L2E2 : L2E;
        d[o] = f2b(s[o] * scale);
    } else if (idx < 262144) {
        int local = idx - 147456;
        int mt = local >> 14, o = local & 16383;
        int r = o >> 7, c = o & 127;
        const float* s; ushort_t* d;
        if (mt < 3)      { s = gWl + (size_t)mt * 16384;       d = WlTb + (size_t)mt * 16384; }
        else if (mt < 6) { s = gWr + (size_t)(mt - 3) * 16384; d = WrTb + (size_t)(mt - 3) * 16384; }
        else             { s = fcW1;                            d = W1Tb; }
        d[c * 128 + r] = f2b(s[r * 128 + c]);
    } else if (idx < 264192) {
        int o = idx - 262144;
        int j = o >> 7, k = o & 127;
        W2Tb[o] = (j < OO) ? f2b(fcW2[k * OO + j]) : (ushort_t)0;
    }
}

// ---------------------------------------------------------------------------
extern "C" void kernel_launch(void* const* d_in, const int* in_sizes, int n_in,
                              void* d_out, int out_size, void* d_ws, size_t ws_size,
                              hipStream_t stream) {
    const float* x     = (const float*)d_in[0];
    const int*   ei    = (const int*)d_in[1];
    const int*   src   = ei;
    const int*   dst   = ei + EE;
    const float* ea    = (const float*)d_in[2];
    const float* Wih0  = (const float*)d_in[3];
    const float* Whh0  = (const float*)d_in[4];
    const float* bih0  = (const float*)d_in[5];
    const float* bhh0  = (const float*)d_in[6];
    const float* Wih1  = (const float*)d_in[7];
    const float* Whh1  = (const float*)d_in[8];
    const float* bih1  = (const float*)d_in[9];
    const float* bhh1  = (const float*)d_in[10];
    const float* gWl   = (const float*)d_in[11];
    const float* gbl   = (const float*)d_in[12];
    const float* gWr   = (const float*)d_in[13];
    const float* gbr   = (const float*)d_in[14];
    const float* gWe   = (const float*)d_in[15];
    const float* gatt  = (const float*)d_in[16];
    const float* gbias = (const float*)d_in[17];
    const float* lng   = (const float*)d_in[18];
    const float* lnb   = (const float*)d_in[19];
    const float* fcW1  = (const float*)d_in[20];
    const float* fcb1  = (const float*)d_in[21];
    const float* fcW2  = (const float*)d_in[22];
    const float* fcb2  = (const float*)d_in[23];
    float* out = (float*)d_out;
    float* ws  = (float*)d_ws;

    const size_t NH = (size_t)NN * HH;   // 6.4M elems

    // ushort region
    ushort_t* h1b   = (ushort_t*)ws;          // NH
    ushort_t* xlb   = h1b + NH;               // NH
    ushort_t* xrb   = xlb + NH;               // NH
    ushort_t* Whh0b = xrb + NH;               // 49152
    ushort_t* Wih1b = Whh0b + 49152;
    ushort_t* Whh1b = Wih1b + 49152;
    ushort_t* WlTb  = Whh1b + 49152;          // 3*16384
    ushort_t* WrTb  = WlTb + 49152;           // 3*16384
    ushort_t* W1Tb  = WrTb + 49152;           // 16384
    ushort_t* W2Tb  = W1Tb + 16384;           // 2048

    float* p    = ws + (3 * NH + 5 * 49152 + 16384 + 2048) / 2;
    float* h1f  = p; p += NH;
    int* deg    = (int*)p;                    // NN
    int2* rbdeg = (int2*)(deg + NN);          // NN int2
    int* cursor = (int*)(rbdeg + NN);         // NN
    int* gcnt   = cursor + NN;                // 4
    int* dhist  = gcnt + 4;                   // 512
    int* dcur   = dhist + 512;                // 512
    int* perm   = dcur + 512;                 // NN
    int* pad_   = perm + NN;                  // align int2
    int2* edgeS = (int2*)(pad_ + ((NN & 1) ? 1 : 0) + 2);  // EE int2 (8B-aligned)

    // --- weight conversions + degree histogram (single merged launch) ---
    hipMemsetAsync(deg, 0, (size_t)NN * sizeof(int), stream);
    hipMemsetAsync(gcnt, 0, (4 + 512) * sizeof(int), stream);   // gcnt + dhist
    conv_cnt<<<1032 + (EE + 255) / 256, 256, 0, stream>>>(
        Whh0, Wih1, Whh1, gWl, gWr, fcW1, fcW2,
        Whh0b, Wih1b, Whh1b, WlTb, WrTb, W1Tb, W2Tb, dst, deg);

    // --- CSR segment allocation + degree histogram; then 512-bin scan ---
    csr_alloc<<<(NN + 255) / 256, 256, 0, stream>>>(deg, rbdeg, cursor, gcnt, dhist);
    dsort_scan<<<1, 512, 0, stream>>>(dhist, dcur);

    // --- GRU (768-block grid, 782 tiles) + csr_fill + sort-scatter piggyback ---
    gru_all<<<GRU_GRID + FILLB + SORTB, 512, 0, stream>>>(
        x, Whh0b, Wih0, bih0, bhh0, Wih1b, Whh1b, bih1, bhh1, h1f, h1b,
        src, dst, ea, cursor, edgeS, deg, dcur, perm);

    // --- GAT layers (degree-sorted schedule) ---
    const int dualBlocks = (NN + 127) / 128;   // 391
    const int fusedBlocks = (NN + 3) / 4;      // 12500
    for (int l = 0; l < LLAYERS; ++l) {
        gemm_dual<<<dualBlocks, 256, 0, stream>>>(h1b, WlTb + (size_t)l * 16384,
                                                  WrTb + (size_t)l * 16384,
                                                  gbl + l * HH, gbr + l * HH, xlb, xrb);
        gat_fused<<<fusedBlocks, 256, 0, stream>>>(rbdeg, edgeS, perm, xlb, xrb,
                                                   gWe + l * HH, gatt + l * HH,
                                                   gbias + l * HH, lng + l * HH, lnb + l * HH,
                                                   h1f, h1b);
    }

    // --- FC head (fused FC1+FC2, 32 rows/wave) ---
    fc_head<<<dualBlocks, 256, 0, stream>>>(h1b, W1Tb, fcb1, W2Tb, fcb2, out);
}

// Round 17
// 589.843 us; speedup vs baseline: 1.4664x; 1.4664x over previous
//
#include <hip/hip_runtime.h>

#define NN 50000
#define EE 800000
#define TT 12
#define HH 128
#define LLAYERS 3
#define OO 12

#define GRU_TILES 782      // ceil(NN/64)
#define GRU_GRID  768      // 3 * 256 CUs exactly

typedef __attribute__((ext_vector_type(8))) short short8;    // 8 bf16 = 4 VGPRs
typedef __attribute__((ext_vector_type(4))) float float4v;   // MFMA acc
typedef unsigned short ushort_t;

#define MFMA_BF16 __builtin_amdgcn_mfma_f32_16x16x32_bf16

#define L2E  1.4426950408889634f
#define L2E2 2.8853900817779268f

#if __has_builtin(__builtin_amdgcn_exp2f)
#define EXP2(x) __builtin_amdgcn_exp2f(x)
#else
#define EXP2(x) __expf((x) * 0.6931471805599453f)
#endif

__device__ __forceinline__ ushort_t f2b(float f) {   // fp32 -> bf16 RNE
    union { float f; unsigned u; } v; v.f = f;
    unsigned u = v.u;
    return (ushort_t)((u + 0x7FFFu + ((u >> 16) & 1u)) >> 16);
}
__device__ __forceinline__ float b2f(ushort_t b) {
    union { unsigned u; float f; } v; v.u = ((unsigned)b) << 16; return v.f;
}
__device__ __forceinline__ short8 ld8(const ushort_t* p) { return *(const short8*)p; }

__device__ __forceinline__ float rcpf_(float x) { return __builtin_amdgcn_rcpf(x); }
// Inputs pre-scaled: y = log2e * x_true  -> sigmoid(x_true)
__device__ __forceinline__ float sig2(float y) { return rcpf_(1.f + EXP2(-y)); }
// y = 2*log2e * x_true -> tanh(x_true)
__device__ __forceinline__ float tanh2(float y) {
    return fmaf(2.f, rcpf_(1.f + EXP2(-y)), -1.f);
}

// Old-style [R][128] tile helpers (used by fc_head only; R<=32).
__device__ __forceinline__ short8 lds_frag(const ushort_t* tile, int row, int kb) {
    int off = (row << 8) + kb;
    off ^= (row & 7) << 4;
    return *(const short8*)((const char*)tile + off);
}
__device__ __forceinline__ void lds_wr16(ushort_t* tile, int row, int cb, ushort_t v) {
    int off = (row << 8) + cb;
    off ^= (row & 7) << 4;
    *(ushort_t*)((char*)tile + off) = v;
}

#define MSTRIDE 132   // fp32 master stride: bank=(4rl+jj)%32 -> free 2-way only

// ---------------------------------------------------------------------------
// Persistent 2-layer GRU + csr_fill piggyback.
// Blocks [0,768): GRU, tiles {b, b+768 if < 782} (64 nodes each). Weight
// fragments (144 regs, exp2-prescaled) loaded ONCE, reused across tiles.
// Blocks [768,...): csr_fill edge scatter (absorbed into GRU stagger),
// writing packed (src, ea) int2.
// One barrier per t-step. fp32 masters in LDS. Both rt loops unrolled 2x.
// ---------------------------------------------------------------------------
__global__ __launch_bounds__(512, 2)
void gru_all(const float* __restrict__ x,
             const ushort_t* __restrict__ Whh0b, const float* __restrict__ Wih0,
             const float* __restrict__ bih0, const float* __restrict__ bhh0,
             const ushort_t* __restrict__ Wih1b, const ushort_t* __restrict__ Whh1b,
             const float* __restrict__ bih1, const float* __restrict__ bhh1,
             float* __restrict__ h1f, ushort_t* __restrict__ h1b,
             const int* __restrict__ src, const int* __restrict__ dst,
             const float* __restrict__ ea, int* __restrict__ cursor,
             int2* __restrict__ edgeS) {
    __shared__ ushort_t h0sA[9216], h0sB[9216], h1sA[9216], h1sB[9216]; // 18432 B each
    __shared__ float h0m[64 * MSTRIDE], h1m[64 * MSTRIDE];              // 33792 B each
    __shared__ float xsh[768];                                          // [12][64]

    // ---- csr_fill blocks (uniform per-block branch; no barriers used) ----
    if (blockIdx.x >= GRU_GRID) {
        int e = (blockIdx.x - GRU_GRID) * 512 + threadIdx.x;
        if (e < EE) {
            int pos = atomicAdd(&cursor[dst[e]], 1);
            edgeS[pos] = make_int2(src[e], __float_as_int(ea[e]));
        }
        return;
    }

    const int tid = threadIdx.x;
    const int wv = tid >> 6, lane = tid & 63;
    const int cl = lane & 15, kg = lane >> 4;
    const int jj = wv * 16 + cl;          // owned hidden column

    // --- persistent weight fragments (loaded once; R/Z rows pre-scaled by
    //     log2e, N rows by 2*log2e in conv_cnt) ---
    short8 w0[3][4], wxx[3][4], whh[3][4];
#pragma unroll
    for (int g = 0; g < 3; ++g)
#pragma unroll
        for (int ks = 0; ks < 4; ++ks) {
            const size_t ro = (size_t)(g * 128 + jj) * HH + ks * 32 + kg * 8;
            w0[g][ks]  = ld8(Whh0b + ro);
            wxx[g][ks] = ld8(Wih1b + ro);
            whh[g][ks] = ld8(Whh1b + ro);
        }
    const float wiR = Wih0[jj] * L2E, wiZ = Wih0[jj + 128] * L2E, wiN = Wih0[jj + 256] * L2E2;
    const float b0R = (bih0[jj] + bhh0[jj]) * L2E;
    const float b0Z = (bih0[jj + 128] + bhh0[jj + 128]) * L2E;
    const float b0N = bih0[jj + 256] * L2E2;
    const float c0N = bhh0[jj + 256] * L2E2;
    const float b1R = (bih1[jj] + bhh1[jj]) * L2E;
    const float b1Z = (bih1[jj + 128] + bhh1[jj + 128]) * L2E;
    const float b1N = bih1[jj + 256] * L2E2;
    const float c1N = bhh1[jj + 256] * L2E2;

    // LDS address precompute
    const int rdl = kg * 288 + cl * 16;                      // + ks*4608 + rt*1152
    const int ksw = jj >> 5;
    const int kcw = (jj >> 3) & 3;
    const int wbase = (ksw * 16 + kcw) * 288 + kg * 64 + (jj & 7) * 2; // + rt*1152 + i*16

#pragma unroll 1
    for (int tile = blockIdx.x; tile < GRU_TILES; tile += GRU_GRID) {
        const int r0 = tile * 64;

        for (int q = tid; q < 768; q += 512) {
            int tt = q >> 6, row = q & 63;                   // xsh[t][row]
            int node = r0 + row;
            xsh[q] = (node < NN) ? x[(size_t)node * TT + tt] : 0.f;
        }
        // zero only the A buffers (B buffers fully written before first read;
        // after 12 swaps (even) pointers return to A for the next tile)
        for (int q = tid; q < 4608; q += 512) {
            ((unsigned*)h0sA)[q] = 0u; ((unsigned*)h1sA)[q] = 0u;
        }
        for (int q = tid; q < 64 * MSTRIDE; q += 512) { h0m[q] = 0.f; h1m[q] = 0.f; }
        __syncthreads();

        ushort_t* h0c = h0sA; ushort_t* h0n = h0sB;
        ushort_t* h1c = h1sA; ushort_t* h1n = h1sB;

#pragma unroll 1
        for (int t = 0; t < TT; ++t) {
            const float* xrow = xsh + t * 64;
            // ---------------- layer 0: read h0c, write h0n ----------------
#pragma unroll 2
            for (int rt = 0; rt < 4; ++rt) {
                short8 a[4];
#pragma unroll
                for (int ks = 0; ks < 4; ++ks)
                    a[ks] = *(const short8*)((const char*)h0c + ks * 4608 + rt * 1152 + rdl);
                float4v aR = {0,0,0,0}, aZ = {0,0,0,0}, aN = {0,0,0,0};
#pragma unroll
                for (int ks = 0; ks < 4; ++ks) {
                    aR = MFMA_BF16(a[ks], w0[0][ks], aR, 0, 0, 0);
                    aZ = MFMA_BF16(a[ks], w0[1][ks], aZ, 0, 0, 0);
                    aN = MFMA_BF16(a[ks], w0[2][ks], aN, 0, 0, 0);
                }
#pragma unroll
                for (int i = 0; i < 4; ++i) {
                    const int rl = rt * 16 + kg * 4 + i;
                    float xv = xrow[rl];
                    float hold = h0m[rl * MSTRIDE + jj];
                    float r = sig2(fmaf(xv, wiR, b0R) + aR[i]);
                    float z = sig2(fmaf(xv, wiZ, b0Z) + aZ[i]);
                    float nn2 = tanh2(fmaf(xv, wiN, b0N) + r * (aN[i] + c0N));
                    float hn = fmaf(z, hold - nn2, nn2);
                    h0m[rl * MSTRIDE + jj] = hn;
                    *(ushort_t*)((char*)h0n + wbase + rt * 1152 + i * 16) = f2b(hn);
                }
            }
            __syncthreads();   // the ONLY barrier per t-step
            // ---------------- layer 1: read h0n,h1c, write h1n ----------------
#pragma unroll 2
            for (int rt = 0; rt < 4; ++rt) {
                short8 an[4], a1[4];
#pragma unroll
                for (int ks = 0; ks < 4; ++ks) {
                    an[ks] = *(const short8*)((const char*)h0n + ks * 4608 + rt * 1152 + rdl);
                    a1[ks] = *(const short8*)((const char*)h1c + ks * 4608 + rt * 1152 + rdl);
                }
                // R/Z: gx+gh accumulate into ONE chain; N needs gh separate.
                float4v gR = {0,0,0,0}, gZ = {0,0,0,0}, xN = {0,0,0,0}, hN = {0,0,0,0};
#pragma unroll
                for (int ks = 0; ks < 4; ++ks) {
                    gR = MFMA_BF16(an[ks], wxx[0][ks], gR, 0, 0, 0);
                    gZ = MFMA_BF16(an[ks], wxx[1][ks], gZ, 0, 0, 0);
                    xN = MFMA_BF16(an[ks], wxx[2][ks], xN, 0, 0, 0);
                    gR = MFMA_BF16(a1[ks], whh[0][ks], gR, 0, 0, 0);
                    gZ = MFMA_BF16(a1[ks], whh[1][ks], gZ, 0, 0, 0);
                    hN = MFMA_BF16(a1[ks], whh[2][ks], hN, 0, 0, 0);
                }
#pragma unroll
                for (int i = 0; i < 4; ++i) {
                    const int rl = rt * 16 + kg * 4 + i;
                    float hold = h1m[rl * MSTRIDE + jj];
                    float r = sig2(gR[i] + b1R);
                    float z = sig2(gZ[i] + b1Z);
                    float nn2 = tanh2(xN[i] + b1N + r * (hN[i] + c1N));
                    float hn = fmaf(z, hold - nn2, nn2);
                    h1m[rl * MSTRIDE + jj] = hn;
                    *(ushort_t*)((char*)h1n + wbase + rt * 1152 + i * 16) = f2b(hn);
                }
            }
            // no barrier: layer0@t+1 only touches h0 buffers whose readers all
            // completed before the barrier above (round-10 proof).
            ushort_t* tmp0 = h0c; h0c = h0n; h0n = tmp0;
            ushort_t* tmp1 = h1c; h1c = h1n; h1n = tmp1;
        }

        // write h1 out (masters owner-lane; no sync needed)
#pragma unroll
        for (int rt = 0; rt < 4; ++rt)
#pragma unroll
            for (int i = 0; i < 4; ++i) {
                const int rl = rt * 16 + kg * 4 + i;
                int node = r0 + rl;
                if (node < NN) {
                    float v = h1m[rl * MSTRIDE + jj];
                    const size_t off = (size_t)node * HH + jj;
                    h1f[off] = v;
                    h1b[off] = f2b(v);
                }
            }
        // barrier before next tile reuses/zeroes the LDS this tile just read
        __syncthreads();
    }
}

// ---------------------------------------------------------------------------
// Dual bf16 GEMM, 32 rows/wave: B-fragments loaded once feed two row-halves.
// ---------------------------------------------------------------------------
__global__ __launch_bounds__(256)
void gemm_dual(const ushort_t* __restrict__ A,
               const ushort_t* __restrict__ B1, const ushort_t* __restrict__ B2,
               const float* __restrict__ bias1, const float* __restrict__ bias2,
               ushort_t* __restrict__ C1, ushort_t* __restrict__ C2) {
    const int wave = threadIdx.x >> 6, lane = threadIdx.x & 63;
    const int r0 = (blockIdx.x * 4 + wave) * 32;
    const int col = lane & 15, kg = lane >> 4;
    const int arow0 = min(r0 + col, NN - 1);
    const int arow1 = min(r0 + 16 + col, NN - 1);
    short8 a0[4], a1[4];
#pragma unroll
    for (int ks = 0; ks < 4; ++ks) {
        a0[ks] = ld8(A + (size_t)arow0 * HH + ks * 32 + kg * 8);
        a1[ks] = ld8(A + (size_t)arow1 * HH + ks * 32 + kg * 8);
    }
#pragma unroll
    for (int j0 = 0; j0 < 8; ++j0) {
        float4v c10 = {0,0,0,0}, c11 = {0,0,0,0}, c20 = {0,0,0,0}, c21 = {0,0,0,0};
        const ushort_t* p1 = B1 + (size_t)(j0 * 16 + col) * HH + kg * 8;
        const ushort_t* p2 = B2 + (size_t)(j0 * 16 + col) * HH + kg * 8;
#pragma unroll
        for (int ks = 0; ks < 4; ++ks) {
            short8 b1v = ld8(p1 + ks * 32);
            short8 b2v = ld8(p2 + ks * 32);
            c10 = MFMA_BF16(a0[ks], b1v, c10, 0, 0, 0);
            c11 = MFMA_BF16(a1[ks], b1v, c11, 0, 0, 0);
            c20 = MFMA_BF16(a0[ks], b2v, c20, 0, 0, 0);
            c21 = MFMA_BF16(a1[ks], b2v, c21, 0, 0, 0);
        }
        const int jj = j0 * 16 + col;
        const float b1 = bias1[jj], b2 = bias2[jj];
#pragma unroll
        for (int i = 0; i < 4; ++i) {
            int node0 = r0 + kg * 4 + i;
            int node1 = node0 + 16;
            if (node0 < NN) {
                C1[(size_t)node0 * HH + jj] = f2b(c10[i] + b1);
                C2[(size_t)node0 * HH + jj] = f2b(c20[i] + b2);
            }
            if (node1 < NN) {
                C1[(size_t)node1 * HH + jj] = f2b(c11[i] + b1);
                C2[(size_t)node1 * HH + jj] = f2b(c21[i] + b2);
            }
        }
    }
}

// ---------------------------------------------------------------------------
// CSR segment allocation (disjoint, not node-ordered). Writes packed
// (rowbeg, deg) int2 for gat_fused's single 8B load.
// ---------------------------------------------------------------------------
__global__ void csr_alloc(const int* __restrict__ deg, int2* __restrict__ rbdeg,
                          int* __restrict__ cursor, int* __restrict__ gcnt) {
    int n = blockIdx.x * 256 + threadIdx.x;
    int ln = threadIdx.x & 63;
    int d = (n < NN) ? deg[n] : 0;
    int s = d;
#pragma unroll
    for (int off = 1; off < 64; off <<= 1) {
        int t = __shfl_up(s, off);
        if (ln >= off) s += t;
    }
    int base = 0;
    if (ln == 63) base = atomicAdd(gcnt, s);
    base = __shfl(base, 63);
    int excl = base + s - d;
    if (n < NN) { rbdeg[n] = make_int2(excl, d); cursor[n] = excl; }
}

// ---------------------------------------------------------------------------
// Fused GAT (depth-1 prefetch, packed edgeS): one wave per dst node;
// 4 edges in parallel (16 lanes each, 8 ch/lane), next-group prefetch hides
// the 256B xl gather. No-max softmax. Then bias + LN + ELU + residual.
// ---------------------------------------------------------------------------
__global__ __launch_bounds__(256)
void gat_fused(const int2* __restrict__ rbdeg,
               const int2* __restrict__ edgeS,
               const ushort_t* __restrict__ xlb, const ushort_t* __restrict__ xrb,
               const float* __restrict__ We, const float* __restrict__ att,
               const float* __restrict__ gbias, const float* __restrict__ gamma,
               const float* __restrict__ beta,
               float* __restrict__ h1f, ushort_t* __restrict__ h1b) {
    const int node = (blockIdx.x * 256 + threadIdx.x) >> 6;
    const int lane = threadIdx.x & 63;
    if (node >= NN) return;
    const int g = lane >> 4, gl = lane & 15;
    const int cb = gl * 8;                      // this lane's channel base

    short8 xrv = ld8(xrb + (size_t)node * HH + cb);
    float xr[8], Wv[8], Av[8];
#pragma unroll
    for (int c = 0; c < 8; ++c) xr[c] = b2f((ushort_t)xrv[c]);
    *(float4*)&Wv[0] = *(const float4*)(We + cb);
    *(float4*)&Wv[4] = *(const float4*)(We + cb + 4);
    *(float4*)&Av[0] = *(const float4*)(att + cb);
    *(float4*)&Av[4] = *(const float4*)(att + cb + 4);

    const int2 bd = rbdeg[node];
    const int beg = bd.x;
    const int end = beg + bd.y;
    float acc[8] = {};
    float den = 0.f;

    if (beg < end) {
        // prime the pipeline
        bool valid = (beg + g) < end;
        int es = min(beg + g, end - 1);
        int2 ed = edgeS[es];
        short8 xlv = ld8(xlb + (size_t)ed.x * HH + cb);
        for (int base = beg; base < end; base += 4) {
            // prefetch next group (uniform branch: base/end wave-uniform)
            int nbase = base + 4;
            int2 ed2 = ed; short8 xlv2 = {};
            bool nvalid = false;
            if (nbase < end) {
                nvalid = (nbase + g) < end;
                int nes = min(nbase + g, end - 1);
                ed2 = edgeS[nes];
                xlv2 = ld8(xlb + (size_t)ed2.x * HH + cb);
            }
            // compute current group
            float ev = __int_as_float(ed.y);
            float xl[8];
            float p = 0.f;
#pragma unroll
            for (int c = 0; c < 8; ++c) {
                xl[c] = b2f((ushort_t)xlv[c]);
                float m = xl[c] + xr[c] + ev * Wv[c];
                m = (m > 0.f) ? m : 0.2f * m;
                p = fmaf(m, Av[c], p);
            }
            p += __shfl_xor(p, 1);
            p += __shfl_xor(p, 2);              // head score (4-lane quad)
            float w = valid ? __expf(p) : 0.f;
            den += w;
#pragma unroll
            for (int c = 0; c < 8; ++c) acc[c] = fmaf(w, xl[c], acc[c]);
            // rotate
            valid = nvalid; ed = ed2; xlv = xlv2;
        }
    }
    // cross-group (edge-slot) reduce
#pragma unroll
    for (int c = 0; c < 8; ++c) {
        acc[c] += __shfl_xor(acc[c], 16);
        acc[c] += __shfl_xor(acc[c], 32);
    }
    den += __shfl_xor(den, 16);
    den += __shfl_xor(den, 32);

    float invd = 1.f / fmaxf(den, 1e-16f);
    float gb[8];
    *(float4*)&gb[0] = *(const float4*)(gbias + cb);
    *(float4*)&gb[4] = *(const float4*)(gbias + cb + 4);
    float o[8], s1 = 0.f, s2 = 0.f;
#pragma unroll
    for (int c = 0; c < 8; ++c) {
        o[c] = acc[c] * invd + gb[c];
        s1 += o[c];
        s2 = fmaf(o[c], o[c], s2);
    }
#pragma unroll
    for (int d = 1; d < 16; d <<= 1) {
        s1 += __shfl_xor(s1, d);
        s2 += __shfl_xor(s2, d);
    }
    float mean = s1 * (1.f / 128.f);
    float var = s2 * (1.f / 128.f) - mean * mean;
    float inv = rsqrtf(var + 1e-5f);

    if (g == 0) {
        float gm[8], bt[8], hv[8];
        *(float4*)&gm[0] = *(const float4*)(gamma + cb);
        *(float4*)&gm[4] = *(const float4*)(gamma + cb + 4);
        *(float4*)&bt[0] = *(const float4*)(beta + cb);
        *(float4*)&bt[4] = *(const float4*)(beta + cb + 4);
        *(float4*)&hv[0] = *(const float4*)(h1f + (size_t)node * HH + cb);
        *(float4*)&hv[4] = *(const float4*)(h1f + (size_t)node * HH + cb + 4);
        short8 pk;
#pragma unroll
        for (int c = 0; c < 8; ++c) {
            float y = (o[c] - mean) * inv * gm[c] + bt[c];
            y = (y > 0.f) ? y : expm1f(y);
            hv[c] += y;
            pk[c] = (short)f2b(hv[c]);
        }
        *(float4*)(h1f + (size_t)node * HH + cb)     = *(float4*)&hv[0];
        *(float4*)(h1f + (size_t)node * HH + cb + 4) = *(float4*)&hv[4];
        *(short8*)(h1b + (size_t)node * HH + cb) = pk;
    }
}

// ---------------------------------------------------------------------------
// Fused FC head, 32 rows/wave: out = relu(h1@W1^T+b1) @ W2 + b2 via LDS.
// ---------------------------------------------------------------------------
__global__ __launch_bounds__(256)
void fc_head(const ushort_t* __restrict__ A, const ushort_t* __restrict__ W1b,
             const float* __restrict__ b1, const ushort_t* __restrict__ W2b,
             const float* __restrict__ b2, float* __restrict__ out) {
    __shared__ ushort_t hs[4][4096];   // [32][128] per wave
    const int wave = threadIdx.x >> 6, lane = threadIdx.x & 63;
    const int r0 = (blockIdx.x * 4 + wave) * 32;
    const int col = lane & 15, kg = lane >> 4;
    const int arow0 = min(r0 + col, NN - 1);
    const int arow1 = min(r0 + 16 + col, NN - 1);
    short8 a0[4], a1[4];
#pragma unroll
    for (int ks = 0; ks < 4; ++ks) {
        a0[ks] = ld8(A + (size_t)arow0 * HH + ks * 32 + kg * 8);
        a1[ks] = ld8(A + (size_t)arow1 * HH + ks * 32 + kg * 8);
    }
#pragma unroll
    for (int j0 = 0; j0 < 8; ++j0) {
        float4v acc0 = {0,0,0,0}, acc1 = {0,0,0,0};
        const ushort_t* bp = W1b + (size_t)(j0 * 16 + col) * HH + kg * 8;
#pragma unroll
        for (int ks = 0; ks < 4; ++ks) {
            short8 bv = ld8(bp + ks * 32);
            acc0 = MFMA_BF16(a0[ks], bv, acc0, 0, 0, 0);
            acc1 = MFMA_BF16(a1[ks], bv, acc1, 0, 0, 0);
        }
        const int jj = j0 * 16 + col;
        const float bj = b1[jj];
#pragma unroll
        for (int i = 0; i < 4; ++i) {
            lds_wr16(hs[wave], kg * 4 + i, jj * 2, f2b(fmaxf(acc0[i] + bj, 0.f)));
            lds_wr16(hs[wave], 16 + kg * 4 + i, jj * 2, f2b(fmaxf(acc1[i] + bj, 0.f)));
        }
    }
    // second GEMM: [32,128] @ W2b[16 padded cols][128]
    short8 w2f[4];
#pragma unroll
    for (int ks = 0; ks < 4; ++ks)
        w2f[ks] = ld8(W2b + (size_t)col * HH + ks * 32 + kg * 8);
#pragma unroll
    for (int rh = 0; rh < 2; ++rh) {
        short8 f[4];
#pragma unroll
        for (int ks = 0; ks < 4; ++ks)
            f[ks] = lds_frag(hs[wave], rh * 16 + col, ks * 64 + kg * 16);
        float4v acc2 = {0,0,0,0};
#pragma unroll
        for (int ks = 0; ks < 4; ++ks)
            acc2 = MFMA_BF16(f[ks], w2f[ks], acc2, 0, 0, 0);
        if (col < OO) {
            const float bj = b2[col];
#pragma unroll
            for (int i = 0; i < 4; ++i) {
                int node = r0 + rh * 16 + kg * 4 + i;
                if (node < NN) out[(size_t)node * OO + col] = acc2[i] + bj;
            }
        }
    }
}

// ---------------------------------------------------------------------------
// Merged weight-conversion + csr_count kernel. Blocks [0,1032): conversions
// (GRU rows exp2-prescaled: R/Z by log2e, N rows by 2*log2e). Blocks
// [1032,...): degree histogram (independent work, overlapped).
// ---------------------------------------------------------------------------
__global__ void conv_cnt(const float* __restrict__ Whh0, const float* __restrict__ Wih1,
                         const float* __restrict__ Whh1, const float* __restrict__ gWl,
                         const float* __restrict__ gWr, const float* __restrict__ fcW1,
                         const float* __restrict__ fcW2,
                         ushort_t* __restrict__ Whh0b, ushort_t* __restrict__ Wih1b,
                         ushort_t* __restrict__ Whh1b, ushort_t* __restrict__ WlTb,
                         ushort_t* __restrict__ WrTb, ushort_t* __restrict__ W1Tb,
                         ushort_t* __restrict__ W2Tb,
                         const int* __restrict__ dst, int* __restrict__ deg) {
    if (blockIdx.x >= 1032) {
        int e = (blockIdx.x - 1032) * 256 + threadIdx.x;
        if (e < EE) atomicAdd(&deg[dst[e]], 1);
        return;
    }
    int idx = blockIdx.x * 256 + threadIdx.x;
    if (idx < 147456) {
        const float* s; ushort_t* d; int o = idx;
        if (o < 49152)        { s = Whh0; d = Whh0b; }
        else if (o < 98304)   { s = Wih1; d = Wih1b; o -= 49152; }
        else                  { s = Whh1; d = Whh1b; o -= 98304; }
        float scale = (o >= 256 * 128) ? L2E2 : L2E;
        d[o] = f2b(s[o] * scale);
    } else if (idx < 262144) {
        int local = idx - 147456;
        int mt = local >> 14, o = local & 16383;
        int r = o >> 7, c = o & 127;
        const float* s; ushort_t* d;
        if (mt < 3)      { s = gWl + (size_t)mt * 16384;       d = WlTb + (size_t)mt * 16384; }
        else if (mt < 6) { s = gWr + (size_t)(mt - 3) * 16384; d = WrTb + (size_t)(mt - 3) * 16384; }
        else             { s = fcW1;                            d = W1Tb; }
        d[c * 128 + r] = f2b(s[r * 128 + c]);
    } else if (idx < 264192) {
        int o = idx - 262144;
        int j = o >> 7, k = o & 127;
        W2Tb[o] = (j < OO) ? f2b(fcW2[k * OO + j]) : (ushort_t)0;
    }
}

// ---------------------------------------------------------------------------
extern "C" void kernel_launch(void* const* d_in, const int* in_sizes, int n_in,
                              void* d_out, int out_size, void* d_ws, size_t ws_size,
                              hipStream_t stream) {
    const float* x     = (const float*)d_in[0];
    const int*   ei    = (const int*)d_in[1];
    const int*   src   = ei;
    const int*   dst   = ei + EE;
    const float* ea    = (const float*)d_in[2];
    const float* Wih0  = (const float*)d_in[3];
    const float* Whh0  = (const float*)d_in[4];
    const float* bih0  = (const float*)d_in[5];
    const float* bhh0  = (const float*)d_in[6];
    const float* Wih1  = (const float*)d_in[7];
    const float* Whh1  = (const float*)d_in[8];
    const float* bih1  = (const float*)d_in[9];
    const float* bhh1  = (const float*)d_in[10];
    const float* gWl   = (const float*)d_in[11];
    const float* gbl   = (const float*)d_in[12];
    const float* gWr   = (const float*)d_in[13];
    const float* gbr   = (const float*)d_in[14];
    const float* gWe   = (const float*)d_in[15];
    const float* gatt  = (const float*)d_in[16];
    const float* gbias = (const float*)d_in[17];
    const float* lng   = (const float*)d_in[18];
    const float* lnb   = (const float*)d_in[19];
    const float* fcW1  = (const float*)d_in[20];
    const float* fcb1  = (const float*)d_in[21];
    const float* fcW2  = (const float*)d_in[22];
    const float* fcb2  = (const float*)d_in[23];
    float* out = (float*)d_out;
    float* ws  = (float*)d_ws;

    const size_t NH = (size_t)NN * HH;   // 6.4M elems

    // ushort region
    ushort_t* h1b   = (ushort_t*)ws;          // NH
    ushort_t* xlb   = h1b + NH;               // NH
    ushort_t* xrb   = xlb + NH;               // NH
    ushort_t* Whh0b = xrb + NH;               // 49152
    ushort_t* Wih1b = Whh0b + 49152;
    ushort_t* Whh1b = Wih1b + 49152;
    ushort_t* WlTb  = Whh1b + 49152;          // 3*16384
    ushort_t* WrTb  = WlTb + 49152;           // 3*16384
    ushort_t* W1Tb  = WrTb + 49152;           // 16384
    ushort_t* W2Tb  = W1Tb + 16384;           // 2048

    float* p    = ws + (3 * NH + 5 * 49152 + 16384 + 2048) / 2;
    float* h1f  = p; p += NH;
    int* deg    = (int*)p;                    // NN
    int2* rbdeg = (int2*)(deg + NN);          // NN int2
    int* cursor = (int*)(rbdeg + NN);         // NN
    int* gcnt   = cursor + NN;                // 4 (pad; int2-aligned)
    int2* edgeS = (int2*)(gcnt + 4);          // EE int2

    // --- weight conversions + degree histogram (single merged launch) ---
    hipMemsetAsync(deg, 0, (size_t)NN * sizeof(int), stream);
    hipMemsetAsync(gcnt, 0, 4 * sizeof(int), stream);
    conv_cnt<<<1032 + (EE + 255) / 256, 256, 0, stream>>>(
        Whh0, Wih1, Whh1, gWl, gWr, fcW1, fcW2,
        Whh0b, Wih1b, Whh1b, WlTb, WrTb, W1Tb, W2Tb, dst, deg);

    // --- CSR segment allocation (fill is folded into gru_all) ---
    csr_alloc<<<(NN + 255) / 256, 256, 0, stream>>>(deg, rbdeg, cursor, gcnt);

    // --- GRU (balanced 768-block grid, 782 tiles) + csr_fill piggyback ---
    const int fillBlocks = (EE + 511) / 512;   // 1563
    gru_all<<<GRU_GRID + fillBlocks, 512, 0, stream>>>(
        x, Whh0b, Wih0, bih0, bhh0, Wih1b, Whh1b, bih1, bhh1, h1f, h1b,
        src, dst, ea, cursor, edgeS);

    // --- GAT layers ---
    const int dualBlocks = (NN + 127) / 128;   // 391
    const int fusedBlocks = (NN + 3) / 4;      // 12500
    for (int l = 0; l < LLAYERS; ++l) {
        gemm_dual<<<dualBlocks, 256, 0, stream>>>(h1b, WlTb + (size_t)l * 16384,
                                                  WrTb + (size_t)l * 16384,
                                                  gbl + l * HH, gbr + l * HH, xlb, xrb);
        gat_fused<<<fusedBlocks, 256, 0, stream>>>(rbdeg, edgeS, xlb, xrb,
                                                   gWe + l * HH, gatt + l * HH,
                                                   gbias + l * HH, lng + l * HH, lnb + l * HH,
                                                   h1f, h1b);
    }

    // --- FC head (fused FC1+FC2, 32 rows/wave) ---
    fc_head<<<dualBlocks, 256, 0, stream>>>(h1b, W1Tb, fcb1, W2Tb, fcb2, out);
}